// Round 3
// 259.980 us; speedup vs baseline: 1.0924x; 1.0924x over previous
//
#include <hip/hip_runtime.h>

// CRF forward-score + gold-score, MI355X (gfx950).
//
// R7 == R5 resubmitted (R5/R6 both died to "MI355X container failed
// twice" — broker-side failure, no kernel verdict. Third audit found no
// hang/fault vector: uniform barrier, fixed trip counts, in-bounds
// accesses, 264 B LDS, VGPR fits under the (128,2) cap. If this round
// also container-fails, next round bisects with the known-good R4.)
//
// R5: forward/backward TIME SPLIT. The recurrence is linear:
//   beta_511 = D_511 E  D_510 E ... D_1 E beta_0   (D_t = diag(exp(u_t)))
//   1^T beta_511 = y^T x,
//     x = prod_{t=1..255}  (D_t E)   beta_0        (forward,  255 steps)
//     y = prod_{t=511..256}(E^T D_t) 1             (backward, 256 steps)
// Two waves per batch (128-thread block): wave0 runs the forward chain,
// wave1 the backward chain. This halves the serial chain AND gives
// 2 waves/SIMD (2048 waves machine-wide), so the ~40% per-step dependency
// stall of R4 (VALUBusy 61% at 1 wave/SIMD) is filled by the other wave.
//
// Same proven exp-domain recurrence with fresh power-of-two normalization
// (R4): z normalized by exponent of z[0] (readlane 0 -> SALU extract),
// exponents accumulate in an exact INT per chain, applied once at the end:
//   fwd = log(sum_l x[l]*y[l]) + (esumA+esumB)*ln2
// Backward step: w = y .* f_t (lane-local), z = E^T w (readlane broadcast
// + fmac, identical cost to forward), y = z * 2^-e. E^T row l
// (= exp(trans[j*64+l]) over j) loads coalesced across lanes.
// Sentinel structure: E row START = 0 -> x[START]=0 for t>=1;
// E^T row STOP = 0 -> y[STOP]=0 for t<=510. Consistent with reference's
// own fp32 underflow of the -10000 sentinels.
//
// Broadcast stays v_readlane -> SGPR -> v_fmac (R4's winner; LDS paths
// were pipe-bound in R3 and get WORSE at 8 waves/CU).
// Feat prefetch rings: depth 5 (fwd, 255 = 5*51) / depth 4 (bwd,
// 256 = 4*64) so ring indices constant-fold; exp(u_next) computed one
// step early (feats don't feed back). 4 steps x ~800 cyc >> 900-cyc HBM
// latency, so the ring still covers at 2 waves/SIMD.
// __launch_bounds__(128, 2): 2 waves/EU -> VGPR cap 256 (need ~100, the
// 64-reg E block must stay in registers; R1 showed spilling = 450 us).

#define BB 1024
#define TT 512
#define KK 64
#define START_TAG 62

// broadcast lane l's float to all lanes via SGPR (l must be a literal 0..63)
#define RLF(v, l) __uint_as_float((unsigned)__builtin_amdgcn_readlane((int)__float_as_uint(v), (l)))

__global__ __launch_bounds__(128, 2) void crf_fwdbwd_kernel(
    const float* __restrict__ feats,   // [B, T, K]
    const int*   __restrict__ tags,    // [B, T]
    const float* __restrict__ trans,   // [K, K]  trans[i*K+j] = score j -> i
    float*       __restrict__ diff)    // [B]  forward - gold
{
  const int lane = threadIdx.x & 63;   // 0..63 == tag index
  const int wv   = threadIdx.x >> 6;   // 0 = forward chain, 1 = backward
  const int b    = blockIdx.x;

  __shared__ float ysh[KK];
  __shared__ float gs_sh;
  __shared__ int   esumB_sh;

  const float* fb = feats + (size_t)b * TT * KK + lane;

  float beta = 0.0f;                   // wave0's final forward component
  int   esumA = 0;

  if (wv == 0) {
    // ---- E row in registers: e4[jc] = exp(trans[lane][4jc..4jc+3]) ----
    float4 e4[16];
    {
      const float4* trow = (const float4*)(trans + lane * KK);
      #pragma unroll
      for (int jc = 0; jc < 16; ++jc) {
        float4 tv = trow[jc];
        e4[jc] = make_float4(__expf(tv.x), __expf(tv.y),
                             __expf(tv.z), __expf(tv.w));
      }
    }

    float upf[5];
    #pragma unroll
    for (int d = 0; d < 5; ++d) upf[d] = fb[(size_t)(1 + d) * KK];

    beta = (lane == START_TAG) ? 1.0f : 0.0f;
    float f_cur = __expf(upf[0]);      // exp(u_1)

    for (int g = 0; g < 51; ++g) {
      #pragma unroll
      for (int d = 0; d < 5; ++d) {
        const int t = 1 + g * 5 + d;   // 1..255

        float4 a0 = {0.f, 0.f, 0.f, 0.f};
        float4 a1 = {0.f, 0.f, 0.f, 0.f};
        #pragma unroll
        for (int jc = 0; jc < 16; jc += 2) {
          a0.x = fmaf(e4[jc].x,     RLF(beta, 4*jc + 0), a0.x);
          a0.y = fmaf(e4[jc].y,     RLF(beta, 4*jc + 1), a0.y);
          a0.z = fmaf(e4[jc].z,     RLF(beta, 4*jc + 2), a0.z);
          a0.w = fmaf(e4[jc].w,     RLF(beta, 4*jc + 3), a0.w);
          a1.x = fmaf(e4[jc + 1].x, RLF(beta, 4*jc + 4), a1.x);
          a1.y = fmaf(e4[jc + 1].y, RLF(beta, 4*jc + 5), a1.y);
          a1.z = fmaf(e4[jc + 1].z, RLF(beta, 4*jc + 6), a1.z);
          a1.w = fmaf(e4[jc + 1].w, RLF(beta, 4*jc + 7), a1.w);
        }
        float z = ((a0.x + a1.x) + (a0.y + a1.y)) +
                  ((a0.z + a1.z) + (a0.w + a1.w));

        int tn = t + 5; if (tn > 255) tn = 255;
        upf[d] = fb[(size_t)tn * KK];

        unsigned zb = (unsigned)__builtin_amdgcn_readlane((int)__float_as_uint(z), 0);
        float s = __uint_as_float(0x7F000000u - (zb & 0x7F800000u)); // 2^-(e-127)
        esumA += (int)((zb >> 23) & 0xFFu) - 127;
        beta = (z * f_cur) * s;

        f_cur = __expf(upf[(d + 1 < 5) ? d + 1 : 0]);
      }
    }
  } else {
    // ---- E^T row in registers: et4[jc].m = exp(trans[(4jc+m)*K + lane]) ----
    float4 et4[16];
    #pragma unroll
    for (int jc = 0; jc < 16; ++jc) {
      et4[jc].x = __expf(trans[(4*jc + 0) * KK + lane]);
      et4[jc].y = __expf(trans[(4*jc + 1) * KK + lane]);
      et4[jc].z = __expf(trans[(4*jc + 2) * KK + lane]);
      et4[jc].w = __expf(trans[(4*jc + 3) * KK + lane]);
    }

    float upf[4];
    #pragma unroll
    for (int d = 0; d < 4; ++d) upf[d] = fb[(size_t)(511 - d) * KK];

    float y = 1.0f;
    int esum = 0;
    float f_cur = __expf(upf[0]);      // exp(u_511)

    for (int g = 0; g < 64; ++g) {
      #pragma unroll
      for (int d = 0; d < 4; ++d) {
        const int t = 511 - (g * 4 + d);   // 511..256

        float w = y * f_cur;               // f_t applied BEFORE E^T
        float4 a0 = {0.f, 0.f, 0.f, 0.f};
        float4 a1 = {0.f, 0.f, 0.f, 0.f};
        #pragma unroll
        for (int jc = 0; jc < 16; jc += 2) {
          a0.x = fmaf(et4[jc].x,     RLF(w, 4*jc + 0), a0.x);
          a0.y = fmaf(et4[jc].y,     RLF(w, 4*jc + 1), a0.y);
          a0.z = fmaf(et4[jc].z,     RLF(w, 4*jc + 2), a0.z);
          a0.w = fmaf(et4[jc].w,     RLF(w, 4*jc + 3), a0.w);
          a1.x = fmaf(et4[jc + 1].x, RLF(w, 4*jc + 4), a1.x);
          a1.y = fmaf(et4[jc + 1].y, RLF(w, 4*jc + 5), a1.y);
          a1.z = fmaf(et4[jc + 1].z, RLF(w, 4*jc + 6), a1.z);
          a1.w = fmaf(et4[jc + 1].w, RLF(w, 4*jc + 7), a1.w);
        }
        float z = ((a0.x + a1.x) + (a0.y + a1.y)) +
                  ((a0.z + a1.z) + (a0.w + a1.w));

        int tn = t - 4; if (tn < 256) tn = 256;
        upf[d] = fb[(size_t)tn * KK];

        unsigned zb = (unsigned)__builtin_amdgcn_readlane((int)__float_as_uint(z), 0);
        float s = __uint_as_float(0x7F000000u - (zb & 0x7F800000u));
        esum += (int)((zb >> 23) & 0xFFu) - 127;
        y = z * s;

        f_cur = __expf(upf[(d + 1) & 3]);
      }
    }

    ysh[lane] = y;
    if (lane == 0) esumB_sh = esum;

    // ---- gold path score (on the backward wave) ----
    const int* tg = tags + b * TT;
    float gs = 0.0f;
    for (int tt = 1 + lane; tt < TT; tt += 64) {
      int tc = tg[tt];
      int tp = tg[tt - 1];
      gs += trans[tc * KK + tp]
          + feats[(size_t)b * TT * KK + (size_t)tt * KK + tc];
    }
    #pragma unroll
    for (int off = 32; off; off >>= 1) gs += __shfl_xor(gs, off);
    if (lane == 0) gs_sh = gs;
  }

  __syncthreads();

  if (wv == 0) {
    // forward score = log(x . y) + (esumA+esumB)*ln2
    float p = beta * ysh[lane];
    #pragma unroll
    for (int off = 32; off; off >>= 1) p += __shfl_xor(p, off);
    float fwd = __logf(p) + (float)(esumA + esumB_sh) * 0.6931471805599453f;
    if (lane == 0) diff[b] = fwd - gs_sh;
  }
}

__global__ __launch_bounds__(1024) void reduce_mean_kernel(
    const float* __restrict__ diff, float* __restrict__ out)
{
  __shared__ float part[16];
  const int tid = threadIdx.x;
  float v = diff[tid];
  #pragma unroll
  for (int off = 32; off; off >>= 1) v += __shfl_xor(v, off);
  if ((tid & 63) == 0) part[tid >> 6] = v;
  __syncthreads();
  if (tid < 16) {
    float s = part[tid];
    #pragma unroll
    for (int off = 8; off; off >>= 1) s += __shfl_xor(s, off);
    if (tid == 0) out[0] = s * (1.0f / 1024.0f);
  }
}

extern "C" void kernel_launch(void* const* d_in, const int* in_sizes, int n_in,
                              void* d_out, int out_size, void* d_ws, size_t ws_size,
                              hipStream_t stream) {
  const float* feats = (const float*)d_in[0];
  const int*   tags  = (const int*)d_in[1];
  const float* trans = (const float*)d_in[2];
  float* out  = (float*)d_out;
  float* diff = (float*)d_ws;   // 1024 floats of scratch

  crf_fwdbwd_kernel<<<dim3(BB), dim3(128), 0, stream>>>(feats, tags, trans, diff);
  reduce_mean_kernel<<<dim3(1), dim3(1024), 0, stream>>>(diff, out);
}